// Round 6
// baseline (2074.876 us; speedup 1.0000x reference)
//
#include <hip/hip_runtime.h>

typedef unsigned int u32;
typedef unsigned short ushort_t;

typedef __attribute__((ext_vector_type(8)))  short bf16x8;   // 8 bf16 = 4 VGPR
typedef __attribute__((ext_vector_type(16))) float f32x16;   // 32x32 MFMA acc
typedef __attribute__((ext_vector_type(2)))  u32 u32x2;
typedef __attribute__((ext_vector_type(4)))  u32 u32x4;

#define ENS 10
#define NU 256
#define NHID 7
#define IN_DIM 6
#define OUT_DIM 201
#define BATCH 16384

// ---- 32x32x16 bf16 fragment layouts ----
// A: lane l holds m = l&31, k = (l>>5)*8 + j   (j=0..7)
// B: lane l holds n = l&31, k = (l>>5)*8 + j
// C/D: lane l holds col = l&31, row = (r&3) + 8*(r>>2) + 4*(l>>5)

// Unified weight stream: 128 chunks per ensemble = 8 "layers" (7 hidden + final
// padded to N=256) x 16 k-steps. Chunk = [8 ct][64 lanes][8 bf16] = 8192 B.
#define WALL_PER 524288                    // ushorts per ens per plane (128*4096)
#define WALL_TOT (ENS * WALL_PER)          // 5,242,880
#define W0_PER 4096                        // per ens per plane (K pad 6->16)
#define W0_TOT (ENS * W0_PER)
#define XN_TOT ((BATCH / 32) * 512)        // x A-frags per plane

// ws layout (ushort units); total ~22.2 MB
#define O_WAH 0
#define O_WAL (O_WAH + WALL_TOT)
#define O_W0H (O_WAL + WALL_TOT)
#define O_W0L (O_W0H + W0_TOT)
#define O_XH  (O_W0L + W0_TOT)
#define O_XL  (O_XH + XN_TOT)

__device__ __forceinline__ u32 bf16_rne(float f) {
    u32 u = __float_as_uint(f);
    return (u + 0x7FFFu + ((u >> 16) & 1u)) >> 16;
}
__device__ __forceinline__ void split2(float f, u32& h, u32& l) {
    h = bf16_rne(f);
    float fh = __uint_as_float(h << 16);
    l = bf16_rne(f - fh);
}

// unpack 8 packed (hi<<16|lo) u32 -> two bf16x8 frags (proven in rounds 2-4)
__device__ __forceinline__ void unpack8(u32x4 r0, u32x4 r1, bf16x8& hi, bf16x8& lo) {
    union { u32 u[4]; bf16x8 v; } H, L;
    H.u[0] = __builtin_amdgcn_perm(r0.y, r0.x, 0x07060302u);
    H.u[1] = __builtin_amdgcn_perm(r0.w, r0.z, 0x07060302u);
    H.u[2] = __builtin_amdgcn_perm(r1.y, r1.x, 0x07060302u);
    H.u[3] = __builtin_amdgcn_perm(r1.w, r1.z, 0x07060302u);
    L.u[0] = __builtin_amdgcn_perm(r0.y, r0.x, 0x05040100u);
    L.u[1] = __builtin_amdgcn_perm(r0.w, r0.z, 0x05040100u);
    L.u[2] = __builtin_amdgcn_perm(r1.y, r1.x, 0x05040100u);
    L.u[3] = __builtin_amdgcn_perm(r1.w, r1.z, 0x05040100u);
    hi = H.v; lo = L.v;
}

// ---------------- prep kernels ----------------

__global__ __launch_bounds__(256) void prep_wall(const float* __restrict__ Wh,
                                                 const float* __restrict__ Wf,
                                                 ushort_t* __restrict__ dH,
                                                 ushort_t* __restrict__ dL) {
    int i = blockIdx.x * 256 + threadIdx.x;
    if (i >= WALL_TOT) return;
    int j = i & 7, l = (i >> 3) & 63, ct = (i >> 9) & 7, cs = (i >> 12) & 127, e = i >> 19;
    int s = cs & 15, Lp = cs >> 4;
    int k = s * 16 + ((l >> 5) << 3) + j;
    int n = ct * 32 + (l & 31);
    float v;
    if (Lp < NHID) v = Wh[(size_t)(Lp * ENS + e) * 65536 + k * 256 + n];
    else           v = (n < OUT_DIM) ? Wf[((size_t)e * 256 + k) * OUT_DIM + n] : 0.0f;
    u32 h, lo; split2(v, h, lo);
    dH[i] = (ushort_t)h; dL[i] = (ushort_t)lo;
}

__global__ __launch_bounds__(256) void prep_w0(const float* __restrict__ W0,
                                               ushort_t* __restrict__ dH, ushort_t* __restrict__ dL) {
    int i = blockIdx.x * 256 + threadIdx.x;
    if (i >= W0_TOT) return;
    int j = i & 7, l = (i >> 3) & 63, ctg = (i >> 9) & 7, e = i >> 12;
    int k = ((l >> 5) << 3) + j;       // 0..15, valid < 6
    int n = ctg * 32 + (l & 31);
    float v = (k < IN_DIM) ? W0[(e * IN_DIM + k) * 256 + n] : 0.0f;
    u32 h, lo; split2(v, h, lo);
    dH[i] = (ushort_t)h; dL[i] = (ushort_t)lo;
}

__global__ __launch_bounds__(256) void prep_x(const float* __restrict__ x,
                                              ushort_t* __restrict__ dH, ushort_t* __restrict__ dL) {
    int i = blockIdx.x * 256 + threadIdx.x;
    if (i >= XN_TOT) return;
    int j = i & 7, l = (i >> 3) & 63, rt = i >> 9;   // rt = 0..511
    int row = rt * 32 + (l & 31);
    int k = ((l >> 5) << 3) + j;
    float v = (k < IN_DIM) ? x[row * IN_DIM + k] : 0.0f;
    u32 h, lo; split2(v, h, lo);
    dH[i] = (ushort_t)h; dL[i] = (ushort_t)lo;
}

__global__ __launch_bounds__(256) void zero_out_kernel(float* __restrict__ out, int n) {
    int i = blockIdx.x * blockDim.x + threadIdx.x;
    int stride = gridDim.x * blockDim.x;
    for (; i < n; i += stride) out[i] = 0.0f;
}

#define MFMA32(A, B, C) __builtin_amdgcn_mfma_f32_32x32x16_bf16((A), (B), (C), 0, 0, 0)

__device__ __forceinline__ void gl_lds16(const void* g, void* l) {
    __builtin_amdgcn_global_load_lds(
        (const __attribute__((address_space(1))) u32*)g,
        (__attribute__((address_space(3))) u32*)l, 16, 0, 0);
}

// swizzled packed-act index: element (row, d) -> u32 index
__device__ __forceinline__ int act_idx(int row, int d) {
    int cc = d >> 1;
    return row * 256 + (((cc ^ (row & 15)) << 1) + (d & 1));
}

// ---------------- fused MLP: DMA-staged B-hi, packed-swizzled act ----------------
// grid 1280 (XCD-swizzled), 512 thr = 8 waves (2 rg x 4 cg), M=128 rows/WG.
// LDS: act 131072 B + B-hi dbuf 16384 B = 147456 B -> 1 WG/CU, 2 waves/SIMD.
__global__ __launch_bounds__(512, 2)
void mlp_mfma(const ushort_t* __restrict__ wsU,
              const float* __restrict__ b0g, const float* __restrict__ bhg,
              const float* __restrict__ bfg, float* __restrict__ out) {
    __shared__ __align__(16) u32 act[128 * 256];        // packed (hi<<16|lo), swizzled
    __shared__ __align__(16) ushort_t bsl[2][4096];     // B-hi chunk slots (8 KB each)

    const int tid  = threadIdx.x;
    const int lane = tid & 63;
    const int wave = tid >> 6;
    const int rg   = wave >> 2;       // 0..1: rows rg*64..
    const int cg   = wave & 3;        // 0..3: cols cg*64..
    const int l31  = lane & 31;
    const int lh   = lane >> 5;
    const int rxA  = l31 & 15;        // A-read row swizzle key

    const int bid  = blockIdx.x;
    const int work = (bid & 7) * 160 + (bid >> 3);   // bijective XCD swizzle (1280%8==0)
    const int e    = work >> 7;       // ensemble 0..9
    const int rb   = work & 127;      // 128-row block
    const int rowWG = rb * 128;

    const ushort_t* WAHe = wsU + O_WAH + (size_t)e * WALL_PER;
    const ushort_t* WALe = wsU + O_WAL + (size_t)e * WALL_PER;
    const int ct0 = cg * 2;

    f32x16 acc[2][2];
    bf16x8 bloR[2][2];                // B-lo ring: [slot s&1][ctl]

    // ================ layer 0 (K padded 6->16) + pipeline prologue ================
    {
        bf16x8 xh[2], xl[2], b0h[2], b0l[2];
#pragma unroll
        for (int mtl = 0; mtl < 2; ++mtl) {
            int rt = rb * 4 + rg * 2 + mtl;
            size_t xo = ((size_t)rt * 64 + lane) * 8;
            xh[mtl] = *(const bf16x8*)(wsU + O_XH + xo);
            xl[mtl] = *(const bf16x8*)(wsU + O_XL + xo);
        }
#pragma unroll
        for (int ctl = 0; ctl < 2; ++ctl) {
            size_t bo = (size_t)e * W0_PER + (ct0 + ctl) * 512 + lane * 8;
            b0h[ctl] = *(const bf16x8*)(wsU + O_W0H + bo);
            b0l[ctl] = *(const bf16x8*)(wsU + O_W0L + bo);
        }
        // pipeline prologue: B-hi chunk 0 via DMA; B-lo chunks 0,1 to regs
        gl_lds16((const char*)WAHe + (size_t)0 * 8192 + wave * 1024 + lane * 16,
                 &bsl[0][wave * 512]);
#pragma unroll
        for (int ctl = 0; ctl < 2; ++ctl) {
            bloR[0][ctl] = *(const bf16x8*)(WALe + (size_t)0 * 4096 + (ct0 + ctl) * 512 + lane * 8);
            bloR[1][ctl] = *(const bf16x8*)(WALe + (size_t)1 * 4096 + (ct0 + ctl) * 512 + lane * 8);
        }

        f32x16 z = 0.0f;
#pragma unroll
        for (int mtl = 0; mtl < 2; ++mtl)
#pragma unroll
            for (int ctl = 0; ctl < 2; ++ctl) {
                f32x16 a = z;
                a = MFMA32(xh[mtl], b0h[ctl], a);
                a = MFMA32(xl[mtl], b0h[ctl], a);
                a = MFMA32(xh[mtl], b0l[ctl], a);
                acc[mtl][ctl] = a;
            }
        // epilogue -> act (packed, swizzled)
        float bv0 = b0g[e * NU + ct0 * 32 + l31];
        float bv1 = b0g[e * NU + (ct0 + 1) * 32 + l31];
#pragma unroll
        for (int mtl = 0; mtl < 2; ++mtl)
#pragma unroll
            for (int ctl = 0; ctl < 2; ++ctl) {
                int d = cg * 64 + ctl * 32 + l31;
                float bv = ctl ? bv1 : bv0;
#pragma unroll
                for (int r = 0; r < 16; ++r) {
                    int rloc = (r & 3) + 8 * (r >> 2) + 4 * lh;
                    int row  = rg * 64 + mtl * 32 + rloc;
                    float f = fmaxf(acc[mtl][ctl][r] + bv, 0.0f);
                    u32 h, lo; split2(f, h, lo);
                    act[act_idx(row, d)] = (h << 16) | lo;
                }
            }
        asm volatile("s_waitcnt lgkmcnt(0)" ::: "memory");
        __builtin_amdgcn_sched_barrier(0);
    }

    // ================ unified stream: 7 hidden + final (128 chunks) ================
#pragma unroll 1
    for (int Lp = 0; Lp < 8; ++Lp) {
        // preload bias for this layer (issued before s=0's stage; drained by vmcnt)
        float bv0, bv1;
        if (Lp < NHID) {
            const float* bias = bhg + (size_t)(Lp * ENS + e) * NU;
            bv0 = bias[ct0 * 32 + l31];
            bv1 = bias[(ct0 + 1) * 32 + l31];
        } else {
            int o0 = ct0 * 32 + l31, o1 = (ct0 + 1) * 32 + l31;
            bv0 = (o0 < OUT_DIM) ? bfg[e * OUT_DIM + o0] : 0.0f;
            bv1 = (o1 < OUT_DIM) ? bfg[e * OUT_DIM + o1] : 0.0f;
        }
        f32x16 z = 0.0f;
#pragma unroll
        for (int mtl = 0; mtl < 2; ++mtl)
#pragma unroll
            for (int ctl = 0; ctl < 2; ++ctl) acc[mtl][ctl] = z;

#pragma unroll
        for (int s = 0; s < 16; ++s) {
            const int cs = Lp * 16 + s;
            // counted wait for chunk cs's DMA (never drain-0 mid-stream)
            if (s == 0) {
                if (Lp == 0) asm volatile("s_waitcnt vmcnt(4)" ::: "memory");
                else         asm volatile("s_waitcnt vmcnt(2)" ::: "memory");
            } else if (s == 15) {
                if (Lp == 7) asm volatile("s_waitcnt vmcnt(0)" ::: "memory");
                else         asm volatile("s_waitcnt vmcnt(2)" ::: "memory");
            } else {
                asm volatile("s_waitcnt vmcnt(2)" ::: "memory");
            }
            __builtin_amdgcn_s_barrier();

            // stage next B-hi chunk into the other slot (DMA, stays in flight)
            if (cs < 127)
                gl_lds16((const char*)WAHe + (size_t)(cs + 1) * 8192 + wave * 1024 + lane * 16,
                         &bsl[(s + 1) & 1][wave * 512]);

            // B-hi frags from LDS
            bf16x8 bh0 = *(const bf16x8*)&bsl[s & 1][ct0 * 512 + lane * 8];
            bf16x8 bh1 = *(const bf16x8*)&bsl[s & 1][(ct0 + 1) * 512 + lane * 8];
            bf16x8 bl0 = bloR[s & 1][0];
            bf16x8 bl1 = bloR[s & 1][1];

            // A frags from packed swizzled act
            bf16x8 ah[2], al[2];
#pragma unroll
            for (int mtl = 0; mtl < 2; ++mtl) {
                int rbase = (rg * 64 + mtl * 32 + l31) * 256;
                int c0 = s * 8 + lh * 4;
                u32x2 q0 = *(const u32x2*)&act[rbase + (((c0 + 0) ^ rxA) << 1)];
                u32x2 q1 = *(const u32x2*)&act[rbase + (((c0 + 1) ^ rxA) << 1)];
                u32x2 q2 = *(const u32x2*)&act[rbase + (((c0 + 2) ^ rxA) << 1)];
                u32x2 q3 = *(const u32x2*)&act[rbase + (((c0 + 3) ^ rxA) << 1)];
                u32x4 r0; r0.x = q0.x; r0.y = q0.y; r0.z = q1.x; r0.w = q1.y;
                u32x4 r1; r1.x = q2.x; r1.y = q2.y; r1.z = q3.x; r1.w = q3.y;
                unpack8(r0, r1, ah[mtl], al[mtl]);
            }

            __builtin_amdgcn_s_setprio(1);
#pragma unroll
            for (int mtl = 0; mtl < 2; ++mtl) {
                f32x16 a0 = acc[mtl][0], a1 = acc[mtl][1];
                a0 = MFMA32(ah[mtl], bh0, a0);
                a1 = MFMA32(ah[mtl], bh1, a1);
                a0 = MFMA32(al[mtl], bh0, a0);
                a1 = MFMA32(al[mtl], bh1, a1);
                a0 = MFMA32(ah[mtl], bl0, a0);
                a1 = MFMA32(ah[mtl], bl1, a1);
                acc[mtl][0] = a0; acc[mtl][1] = a1;
            }
            __builtin_amdgcn_s_setprio(0);

            // issue B-lo for chunk cs+2 (after last use of slot s&1)
            if (cs < 126) {
#pragma unroll
                for (int ctl = 0; ctl < 2; ++ctl)
                    bloR[s & 1][ctl] = *(const bf16x8*)(WALe + (size_t)(cs + 2) * 4096 +
                                                       (ct0 + ctl) * 512 + lane * 8);
            }
        }

        // all waves done reading act for this layer before overwriting it
        __builtin_amdgcn_s_barrier();

        if (Lp < NHID) {
            // hidden epilogue: bias + relu + split -> act
#pragma unroll
            for (int mtl = 0; mtl < 2; ++mtl)
#pragma unroll
                for (int ctl = 0; ctl < 2; ++ctl) {
                    int d = cg * 64 + ctl * 32 + l31;
                    float bv = ctl ? bv1 : bv0;
#pragma unroll
                    for (int r = 0; r < 16; ++r) {
                        int rloc = (r & 3) + 8 * (r >> 2) + 4 * lh;
                        int row  = rg * 64 + mtl * 32 + rloc;
                        float f = fmaxf(acc[mtl][ctl][r] + bv, 0.0f);
                        u32 h, lo; split2(f, h, lo);
                        act[act_idx(row, d)] = (h << 16) | lo;
                    }
                }
            asm volatile("s_waitcnt lgkmcnt(0)" ::: "memory");
            __builtin_amdgcn_sched_barrier(0);
        } else {
            // final epilogue: strided-mean, out[b][(e*201+o)/10] += 0.1*(y+bias)
#pragma unroll
            for (int mtl = 0; mtl < 2; ++mtl)
#pragma unroll
                for (int ctl = 0; ctl < 2; ++ctl) {
                    int o = cg * 64 + ctl * 32 + l31;
                    if (o < OUT_DIM) {
                        float bv = ctl ? bv1 : bv0;
                        int jo = (e * OUT_DIM + o) / 10;
#pragma unroll
                        for (int r = 0; r < 16; ++r) {
                            int rloc = (r & 3) + 8 * (r >> 2) + 4 * lh;
                            int rowg = rowWG + rg * 64 + mtl * 32 + rloc;
                            atomicAdd(out + (size_t)rowg * OUT_DIM + jo,
                                      0.1f * (acc[mtl][ctl][r] + bv));
                        }
                    }
                }
        }
    }
}

extern "C" void kernel_launch(void* const* d_in, const int* in_sizes, int n_in,
                              void* d_out, int out_size, void* d_ws, size_t ws_size,
                              hipStream_t stream) {
    const float* x  = (const float*)d_in[0];
    const float* W0 = (const float*)d_in[1];
    const float* b0 = (const float*)d_in[2];
    const float* Wh = (const float*)d_in[3];
    const float* bh = (const float*)d_in[4];
    const float* Wf = (const float*)d_in[5];
    const float* bf = (const float*)d_in[6];
    float* out = (float*)d_out;
    ushort_t* ws = (ushort_t*)d_ws;   // needs ~22.2 MB

    prep_wall<<<(WALL_TOT + 255) / 256, 256, 0, stream>>>(Wh, Wf, ws + O_WAH, ws + O_WAL);
    prep_w0<<<(W0_TOT + 255) / 256, 256, 0, stream>>>(W0, ws + O_W0H, ws + O_W0L);
    prep_x <<<(XN_TOT + 255) / 256, 256, 0, stream>>>(x,  ws + O_XH,  ws + O_XL);
    zero_out_kernel<<<2048, 256, 0, stream>>>(out, out_size);

    mlp_mfma<<<dim3(BATCH / 128 * ENS), 512, 0, stream>>>(ws, b0, bh, bf, out);
}

// Round 7
// 534.419 us; speedup vs baseline: 3.8825x; 3.8825x over previous
//
#include <hip/hip_runtime.h>

typedef unsigned int u32;
typedef unsigned short ushort_t;

typedef __attribute__((ext_vector_type(8)))  short bf16x8;   // 8 bf16 = 4 VGPR
typedef __attribute__((ext_vector_type(16))) float f32x16;   // 32x32 MFMA acc

#define ENS 10
#define NU 256
#define NHID 7
#define IN_DIM 6
#define OUT_DIM 201
#define BATCH 16384

// ---- 32x32x16 bf16 fragment layouts ----
// A: lane l holds m = l&31,  k = (l>>5)*8 + j   (j=0..7)
// B: lane l holds n = l&31,  k = (l>>5)*8 + j
// C/D: lane l holds col = l&31, row = (r&3) + 8*(r>>2) + 4*(l>>5)  (r=0..15)

// fragment-array sizes in ushort (bf16) elements, per plane
#define WH_PER 65536                  // per (layer,ens): 16 s * 8 ctg * 64 * 8
#define WH_TOT (NHID * ENS * WH_PER)  // 4,587,520
#define W0_PER 4096                   // per ens: 8 ctg * 64 * 8 (K pad 6->16)
#define W0_TOT (ENS * W0_PER)
#define WF_PER 57344                  // per ens: 16 s * 7 ctg * 64 * 8 (N pad 201->224)
#define WF_TOT (ENS * WF_PER)
#define X_TOT ((BATCH / 32) * 64 * 8) // 262,144 (K pad 6->16)

// ws layout (ushort units); weights ~21.9 MB + P partials 13.8 MB
#define O_WHH 0
#define O_WHL (O_WHH + WH_TOT)
#define O_W0H (O_WHL + WH_TOT)
#define O_W0L (O_W0H + W0_TOT)
#define O_WFH (O_W0L + W0_TOT)
#define O_WFL (O_WFH + WF_TOT)
#define O_XH  (O_WFL + WF_TOT)
#define O_XL  (O_XH + X_TOT)
#define O_P   (O_XL + X_TOT)          // float P[ENS][BATCH][21] from here

#define NG 21    // jo-groups per ensemble (201 consecutive flat channels span 21 groups)
#define RS 264   // act plane row stride (ushort); 528B row: b128-aligned per lane
#define YS 204   // y-staging row stride (float)

__device__ __forceinline__ u32 bf16_rne(float f) {
    u32 u = __float_as_uint(f);
    return (u + 0x7FFFu + ((u >> 16) & 1u)) >> 16;
}
__device__ __forceinline__ void split2(float f, u32& h, u32& l) {
    h = bf16_rne(f);
    float fh = __uint_as_float(h << 16);
    l = bf16_rne(f - fh);
}

// ---------------- prep kernels: fp32 -> hi/lo bf16, B/A-frag-linear ----------------

__global__ __launch_bounds__(256) void prep_wh(const float* __restrict__ Wh,
                                               ushort_t* __restrict__ dH, ushort_t* __restrict__ dL) {
    int i = blockIdx.x * 256 + threadIdx.x;
    if (i >= WH_TOT) return;
    int j = i & 7, l = (i >> 3) & 63, ctg = (i >> 9) & 7, s = (i >> 12) & 15, le = i >> 16;
    int k = s * 16 + ((l >> 5) << 3) + j;
    int n = ctg * 32 + (l & 31);
    float v = Wh[(size_t)le * 65536 + k * 256 + n];
    u32 h, lo; split2(v, h, lo);
    dH[i] = (ushort_t)h; dL[i] = (ushort_t)lo;
}

__global__ __launch_bounds__(256) void prep_w0(const float* __restrict__ W0,
                                               ushort_t* __restrict__ dH, ushort_t* __restrict__ dL) {
    int i = blockIdx.x * 256 + threadIdx.x;
    if (i >= W0_TOT) return;
    int j = i & 7, l = (i >> 3) & 63, ctg = (i >> 9) & 7, e = i >> 12;
    int k = ((l >> 5) << 3) + j;       // 0..15, valid < 6
    int n = ctg * 32 + (l & 31);
    float v = (k < IN_DIM) ? W0[(e * IN_DIM + k) * 256 + n] : 0.0f;
    u32 h, lo; split2(v, h, lo);
    dH[i] = (ushort_t)h; dL[i] = (ushort_t)lo;
}

__global__ __launch_bounds__(256) void prep_wf(const float* __restrict__ Wf,
                                               ushort_t* __restrict__ dH, ushort_t* __restrict__ dL) {
    int i = blockIdx.x * 256 + threadIdx.x;
    if (i >= WF_TOT) return;
    int e = i / WF_PER;
    int idx = i - e * WF_PER;
    int j = idx & 7, l = (idx >> 3) & 63, g = idx >> 9;  // g = s*7+ct, 0..111
    int s = g / 7, ct = g - s * 7;
    int k = s * 16 + ((l >> 5) << 3) + j;
    int n = ct * 32 + (l & 31);
    float v = (n < OUT_DIM) ? Wf[((size_t)e * 256 + k) * OUT_DIM + n] : 0.0f;
    u32 h, lo; split2(v, h, lo);
    dH[i] = (ushort_t)h; dL[i] = (ushort_t)lo;
}

__global__ __launch_bounds__(256) void prep_x(const float* __restrict__ x,
                                              ushort_t* __restrict__ dH, ushort_t* __restrict__ dL) {
    int i = blockIdx.x * 256 + threadIdx.x;
    if (i >= X_TOT) return;
    int j = i & 7, l = (i >> 3) & 63, rt = i >> 9;   // rt = 0..511
    int row = rt * 32 + (l & 31);
    int k = ((l >> 5) << 3) + j;
    float v = (k < IN_DIM) ? x[row * IN_DIM + k] : 0.0f;
    u32 h, lo; split2(v, h, lo);
    dH[i] = (ushort_t)h; dL[i] = (ushort_t)lo;
}

// out[b][jo] = 0.1 * (P[e1][b][jo-base(e1)] + (e2!=e1 ? P[e2][b][jo-base(e2)] : 0))
__global__ __launch_bounds__(256) void reduce_mean(const float* __restrict__ P,
                                                   float* __restrict__ out) {
    int i = blockIdx.x * 256 + threadIdx.x;
    if (i >= BATCH * OUT_DIM) return;
    int b = i / OUT_DIM, jo = i - b * OUT_DIM;
    int f0 = jo * 10;
    int e1 = f0 / OUT_DIM;
    int e2 = (f0 + 9) / OUT_DIM;
    int g1 = jo - (e1 * OUT_DIM) / 10;
    float s = P[((size_t)e1 * BATCH + b) * NG + g1];
    if (e2 != e1) {
        int g2 = jo - (e2 * OUT_DIM) / 10;
        s += P[((size_t)e2 * BATCH + b) * NG + g2];
    }
    out[i] = 0.1f * s;
}

#define MFMA32(A, B, C) __builtin_amdgcn_mfma_f32_32x32x16_bf16((A), (B), (C), 0, 0, 0)

// ---------------- fused MLP: 32x32x16 split-bf16, pipelined A+B ----------------
// grid 5120 (XCD-swizzled); 256 threads = 4 waves; wave cg owns cols
// [cg*64, cg*64+64) (ct tiles ctg0=2cg, 2cg+1) of this WG's 32 batch rows.
// LDS 33.8 KB -> 4 WG/CU (16 waves/CU). NO global atomics: per-ensemble
// group-of-10 partials are reduced in LDS and plain-stored to P.
__global__ __launch_bounds__(256, 4)
void mlp_mfma(const ushort_t* __restrict__ wsU,
              const float* __restrict__ b0g, const float* __restrict__ bhg,
              const float* __restrict__ bfg, float* __restrict__ Pws) {
    __shared__ __align__(16) u32 smem[8448];             // 33,792 B, aliased:
    ushort_t* actH = (ushort_t*)smem;                    //   [32][RS] hi plane
    ushort_t* actL = actH + 32 * RS;                     //   [32][RS] lo plane
    float*    yst  = (float*)smem;                       //   [32][YS] final-y staging

    const int tid  = threadIdx.x;
    const int lane = tid & 63;
    const int cg   = tid >> 6;        // wave 0..3
    const int l31  = lane & 31;
    const int lh   = lane >> 5;       // 0..1
    const int ctg0 = cg * 2;

    // XCD-aware bijective swizzle: 5120 WGs, 8 XCDs, 640/XCD
    const int bid  = blockIdx.x;
    const int work = (bid & 7) * 640 + (bid >> 3);
    const int e    = work >> 9;       // ensemble 0..9
    const int rb   = work & 511;      // row block 0..511
    const int rowWG = rb * 32;

    const size_t lo8 = (size_t)lane * 8;
    const ushort_t* arH = actH + l31 * RS;
    const ushort_t* arL = actL + l31 * RS;
    const int rowb = lh * 4;          // epilogue row base

    f32x16 acc0, acc1;
    bf16x8 Bc0, Bc1, Bc2, Bc3;        // current B: [ctg0 hi, ctg0 lo, ctg0+1 hi, ctg0+1 lo]
    bf16x8 aH, aL;

    // ================ layer 0 (K padded 6->16, single k-step) ================
    {
        const ushort_t* B0H = wsU + O_W0H + (size_t)e * W0_PER;
        const ushort_t* B0L = wsU + O_W0L + (size_t)e * W0_PER;
        Bc0 = *(const bf16x8*)(B0H + (size_t)ctg0 * 512 + lo8);
        Bc1 = *(const bf16x8*)(B0L + (size_t)ctg0 * 512 + lo8);
        Bc2 = *(const bf16x8*)(B0H + (size_t)(ctg0 + 1) * 512 + lo8);
        Bc3 = *(const bf16x8*)(B0L + (size_t)(ctg0 + 1) * 512 + lo8);
        size_t xoff = ((size_t)rb * 64 + lane) * 8;
        aH = *(const bf16x8*)(wsU + O_XH + xoff);
        aL = *(const bf16x8*)(wsU + O_XL + xoff);
        // prefetch hidden layer 0, s=0 B
        const ushort_t* BH0 = wsU + O_WHH + (size_t)e * WH_PER;
        const ushort_t* BL0 = wsU + O_WHL + (size_t)e * WH_PER;
        bf16x8 Bn0 = *(const bf16x8*)(BH0 + (size_t)ctg0 * 512 + lo8);
        bf16x8 Bn1 = *(const bf16x8*)(BL0 + (size_t)ctg0 * 512 + lo8);
        bf16x8 Bn2 = *(const bf16x8*)(BH0 + (size_t)(ctg0 + 1) * 512 + lo8);
        bf16x8 Bn3 = *(const bf16x8*)(BL0 + (size_t)(ctg0 + 1) * 512 + lo8);
        __builtin_amdgcn_sched_barrier(0);

        f32x16 z = 0.0f;
        acc0 = z; acc1 = z;
        acc0 = MFMA32(aH, Bc0, acc0);
        acc0 = MFMA32(aL, Bc0, acc0);
        acc0 = MFMA32(aH, Bc1, acc0);
        acc1 = MFMA32(aH, Bc2, acc1);
        acc1 = MFMA32(aL, Bc2, acc1);
        acc1 = MFMA32(aH, Bc3, acc1);

        float bv0 = b0g[e * NU + ctg0 * 32 + l31];
        float bv1 = b0g[e * NU + (ctg0 + 1) * 32 + l31];
        int colA = ctg0 * 32 + l31, colB = colA + 32;
#pragma unroll
        for (int r = 0; r < 16; ++r) {
            int row = rowb + (r & 3) + 8 * (r >> 2);
            float f0 = fmaxf(acc0[r] + bv0, 0.0f);
            float f1 = fmaxf(acc1[r] + bv1, 0.0f);
            u32 h0, q0, h1, q1;
            split2(f0, h0, q0); split2(f1, h1, q1);
            actH[row * RS + colA] = (ushort_t)h0; actL[row * RS + colA] = (ushort_t)q0;
            actH[row * RS + colB] = (ushort_t)h1; actL[row * RS + colB] = (ushort_t)q1;
        }
        Bc0 = Bn0; Bc1 = Bn1; Bc2 = Bn2; Bc3 = Bn3;
        __syncthreads();
    }

    // ================ 7 hidden layers (K=256, 16 k-steps, A+B pipelined) ================
    const ushort_t* BH = wsU + O_WHH + (size_t)e * WH_PER;
    const ushort_t* BL = wsU + O_WHL + (size_t)e * WH_PER;
#pragma unroll 1
    for (int L = 0; L < NHID; ++L) {
        float bv0 = bhg[(size_t)(L * ENS + e) * NU + ctg0 * 32 + l31];
        float bv1 = bhg[(size_t)(L * ENS + e) * NU + (ctg0 + 1) * 32 + l31];
        f32x16 z = 0.0f;
        acc0 = z; acc1 = z;
        // A for s=0
        aH = *(const bf16x8*)(arH + lh * 8);
        aL = *(const bf16x8*)(arL + lh * 8);

#pragma unroll
        for (int s = 0; s < 16; ++s) {
            bf16x8 aHn, aLn, Bn0, Bn1, Bn2, Bn3;
            if (s < 15) {
                int kn = (s + 1) * 16 + lh * 8;
                aHn = *(const bf16x8*)(arH + kn);
                aLn = *(const bf16x8*)(arL + kn);
                const ushort_t* ph = BH + (size_t)((s + 1) * 8 + ctg0) * 512;
                const ushort_t* pl = BL + (size_t)((s + 1) * 8 + ctg0) * 512;
                Bn0 = *(const bf16x8*)(ph + lo8);
                Bn1 = *(const bf16x8*)(pl + lo8);
                Bn2 = *(const bf16x8*)(ph + 512 + lo8);
                Bn3 = *(const bf16x8*)(pl + 512 + lo8);
            }
            __builtin_amdgcn_sched_barrier(0);
            acc0 = MFMA32(aH, Bc0, acc0);
            acc0 = MFMA32(aL, Bc0, acc0);
            acc0 = MFMA32(aH, Bc1, acc0);
            acc1 = MFMA32(aH, Bc2, acc1);
            acc1 = MFMA32(aL, Bc2, acc1);
            acc1 = MFMA32(aH, Bc3, acc1);
            if (s < 15) {
                aH = aHn; aL = aLn;
                Bc0 = Bn0; Bc1 = Bn1; Bc2 = Bn2; Bc3 = Bn3;
            }
        }

        // prefetch next layer's s=0 B (or final layer's) before the barriers
        if (L < NHID - 1) {
            const ushort_t* nh = BH + (size_t)ENS * WH_PER;
            const ushort_t* nl = BL + (size_t)ENS * WH_PER;
            Bc0 = *(const bf16x8*)(nh + (size_t)ctg0 * 512 + lo8);
            Bc1 = *(const bf16x8*)(nl + (size_t)ctg0 * 512 + lo8);
            Bc2 = *(const bf16x8*)(nh + (size_t)(ctg0 + 1) * 512 + lo8);
            Bc3 = *(const bf16x8*)(nl + (size_t)(ctg0 + 1) * 512 + lo8);
        } else {
            const ushort_t* fh = wsU + O_WFH + (size_t)e * WF_PER;
            const ushort_t* fl = wsU + O_WFL + (size_t)e * WF_PER;
            int c0 = ctg0, c1 = (ctg0 + 1 > 6) ? 6 : ctg0 + 1;
            if (c0 > 6) c0 = 6;
            Bc0 = *(const bf16x8*)(fh + (size_t)c0 * 512 + lo8);
            Bc1 = *(const bf16x8*)(fl + (size_t)c0 * 512 + lo8);
            Bc2 = *(const bf16x8*)(fh + (size_t)c1 * 512 + lo8);
            Bc3 = *(const bf16x8*)(fl + (size_t)c1 * 512 + lo8);
        }

        __syncthreads();   // all act reads of this layer done before overwrite
        int colA = ctg0 * 32 + l31, colB = colA + 32;
#pragma unroll
        for (int r = 0; r < 16; ++r) {
            int row = rowb + (r & 3) + 8 * (r >> 2);
            float f0 = fmaxf(acc0[r] + bv0, 0.0f);
            float f1 = fmaxf(acc1[r] + bv1, 0.0f);
            u32 h0, q0, h1, q1;
            split2(f0, h0, q0); split2(f1, h1, q1);
            actH[row * RS + colA] = (ushort_t)h0; actL[row * RS + colA] = (ushort_t)q0;
            actH[row * RS + colB] = (ushort_t)h1; actL[row * RS + colB] = (ushort_t)q1;
        }
        __syncthreads();
        BH += (size_t)ENS * WH_PER;
        BL += (size_t)ENS * WH_PER;
    }

    // ================ final layer (N padded 201->224 = 7 ct-tiles) ================
    {
        const ushort_t* FH = wsU + O_WFH + (size_t)e * WF_PER;
        const ushort_t* FL = wsU + O_WFL + (size_t)e * WF_PER;
        int c0 = (ctg0 > 6) ? 6 : ctg0;
        int c1 = (ctg0 + 1 > 6) ? 6 : ctg0 + 1;
        f32x16 z = 0.0f;
        acc0 = z; acc1 = z;
        aH = *(const bf16x8*)(arH + lh * 8);
        aL = *(const bf16x8*)(arL + lh * 8);

#pragma unroll
        for (int s = 0; s < 16; ++s) {
            bf16x8 aHn, aLn, Bn0, Bn1, Bn2, Bn3;
            if (s < 15) {
                int kn = (s + 1) * 16 + lh * 8;
                aHn = *(const bf16x8*)(arH + kn);
                aLn = *(const bf16x8*)(arL + kn);
                Bn0 = *(const bf16x8*)(FH + (size_t)((s + 1) * 7 + c0) * 512 + lo8);
                Bn1 = *(const bf16x8*)(FL + (size_t)((s + 1) * 7 + c0) * 512 + lo8);
                Bn2 = *(const bf16x8*)(FH + (size_t)((s + 1) * 7 + c1) * 512 + lo8);
                Bn3 = *(const bf16x8*)(FL + (size_t)((s + 1) * 7 + c1) * 512 + lo8);
            }
            __builtin_amdgcn_sched_barrier(0);
            acc0 = MFMA32(aH, Bc0, acc0);
            acc0 = MFMA32(aL, Bc0, acc0);
            acc0 = MFMA32(aH, Bc1, acc0);
            acc1 = MFMA32(aH, Bc2, acc1);
            acc1 = MFMA32(aL, Bc2, acc1);
            acc1 = MFMA32(aH, Bc3, acc1);
            if (s < 15) {
                aH = aHn; aL = aLn;
                Bc0 = Bn0; Bc1 = Bn1; Bc2 = Bn2; Bc3 = Bn3;
            }
        }

        // ---- NO atomics: stage y into LDS, reduce groups-of-10, store partials ----
        int o0 = ctg0 * 32 + l31;
        int o1 = (ctg0 + 1) * 32 + l31;
        bool v0 = (o0 < OUT_DIM);
        bool v1 = (ctg0 + 1 < 7) && (o1 < OUT_DIM);
        float bf0 = v0 ? bfg[e * OUT_DIM + o0] : 0.0f;
        float bf1 = v1 ? bfg[e * OUT_DIM + o1] : 0.0f;

        __syncthreads();   // all act reads done; safe to overwrite smem with yst
#pragma unroll
        for (int r = 0; r < 16; ++r) {
            int row = rowb + (r & 3) + 8 * (r >> 2);
            if (v0) yst[row * YS + o0] = acc0[r] + bf0;
            if (v1) yst[row * YS + o1] = acc1[r] + bf1;
        }
        __syncthreads();

        // partial sums: P[e][rowWG+row][g] = sum over flatc in [jo*10, jo*10+10)
        // intersected with this ensemble's block [201e, 201e+201)
        const int base_jo = (e * OUT_DIM) / 10;
        const int e201 = e * OUT_DIM;
        for (int it = tid; it < 32 * NG; it += 256) {
            int row = it / NG;
            int g   = it - row * NG;
            int jo  = base_jo + g;
            int f0  = jo * 10;
            float s = 0.0f;
#pragma unroll
            for (int d = 0; d < 10; ++d) {
                int oo = f0 + d - e201;
                if (oo >= 0 && oo < OUT_DIM) s += yst[row * YS + oo];
            }
            Pws[((size_t)e * BATCH + rowWG + row) * NG + g] = s;
        }
    }
}

extern "C" void kernel_launch(void* const* d_in, const int* in_sizes, int n_in,
                              void* d_out, int out_size, void* d_ws, size_t ws_size,
                              hipStream_t stream) {
    const float* x  = (const float*)d_in[0];
    const float* W0 = (const float*)d_in[1];
    const float* b0 = (const float*)d_in[2];
    const float* Wh = (const float*)d_in[3];
    const float* bh = (const float*)d_in[4];
    const float* Wf = (const float*)d_in[5];
    const float* bf = (const float*)d_in[6];
    float* out = (float*)d_out;
    ushort_t* ws = (ushort_t*)d_ws;            // needs ~36 MB
    float* Pws = (float*)(ws + O_P);           // P[ENS][BATCH][NG]

    prep_wh<<<(WH_TOT + 255) / 256, 256, 0, stream>>>(Wh, ws + O_WHH, ws + O_WHL);
    prep_w0<<<(W0_TOT + 255) / 256, 256, 0, stream>>>(W0, ws + O_W0H, ws + O_W0L);
    prep_wf<<<(WF_TOT + 255) / 256, 256, 0, stream>>>(Wf, ws + O_WFH, ws + O_WFL);
    prep_x <<<(X_TOT  + 255) / 256, 256, 0, stream>>>(x,  ws + O_XH,  ws + O_XL);

    mlp_mfma<<<dim3(BATCH / 32 * ENS), 256, 0, stream>>>(ws, b0, bh, bf, Pws);
    reduce_mean<<<(BATCH * OUT_DIM + 255) / 256, 256, 0, stream>>>(Pws, out);
}

// Round 8
// 448.989 us; speedup vs baseline: 4.6212x; 1.1903x over previous
//
#include <hip/hip_runtime.h>

typedef unsigned int u32;
typedef unsigned short ushort_t;

typedef __attribute__((ext_vector_type(8)))  short bf16x8;   // 8 bf16 = 4 VGPR
typedef __attribute__((ext_vector_type(16))) float f32x16;   // 32x32 MFMA acc

#define ENS 10
#define NU 256
#define NHID 7
#define IN_DIM 6
#define OUT_DIM 201
#define BATCH 16384

// ---- 32x32x16 bf16 fragment layouts ----
// A: lane l holds m = l&31,  k = (l>>5)*8 + j   (j=0..7)
// B: lane l holds n = l&31,  k = (l>>5)*8 + j
// C/D: lane l holds col = l&31, row = (r&3) + 8*(r>>2) + 4*(l>>5)  (r=0..15)

// fragment-array sizes in ushort (bf16) elements, per plane
#define WH_PER 65536                  // per (layer,ens): 16 s * 8 ctg * 64 * 8
#define WH_TOT (NHID * ENS * WH_PER)  // 4,587,520
#define W0_PER 4096                   // per ens: 8 ctg * 64 * 8 (K pad 6->16)
#define W0_TOT (ENS * W0_PER)
#define WF_PER 57344                  // per ens: 16 s * 7 ctg * 64 * 8 (N pad 201->224)
#define WF_TOT (ENS * WF_PER)
#define X_TOT ((BATCH / 32) * 64 * 8) // 262,144 (K pad 6->16)

// ws layout (ushort units); weights ~21.9 MB + P partials 13.8 MB
#define O_WHH 0
#define O_WHL (O_WHH + WH_TOT)
#define O_W0H (O_WHL + WH_TOT)
#define O_W0L (O_W0H + W0_TOT)
#define O_WFH (O_W0L + W0_TOT)
#define O_WFL (O_WFH + WF_TOT)
#define O_XH  (O_WFL + WF_TOT)
#define O_XL  (O_XH + X_TOT)
#define O_P   (O_XL + X_TOT)          // float P[ENS][BATCH][21] from here

#define NG 21    // jo-groups per ensemble
#define RS 264   // act plane row stride (ushort)
#define YS 204   // y-staging row stride (float)
#define RT 64    // batch rows per WG

__device__ __forceinline__ u32 bf16_rne(float f) {
    u32 u = __float_as_uint(f);
    return (u + 0x7FFFu + ((u >> 16) & 1u)) >> 16;
}
__device__ __forceinline__ void split2(float f, u32& h, u32& l) {
    h = bf16_rne(f);
    float fh = __uint_as_float(h << 16);
    l = bf16_rne(f - fh);
}

// ---------------- prep kernels: fp32 -> hi/lo bf16, B/A-frag-linear ----------------

__global__ __launch_bounds__(256) void prep_wh(const float* __restrict__ Wh,
                                               ushort_t* __restrict__ dH, ushort_t* __restrict__ dL) {
    int i = blockIdx.x * 256 + threadIdx.x;
    if (i >= WH_TOT) return;
    int j = i & 7, l = (i >> 3) & 63, ctg = (i >> 9) & 7, s = (i >> 12) & 15, le = i >> 16;
    int k = s * 16 + ((l >> 5) << 3) + j;
    int n = ctg * 32 + (l & 31);
    float v = Wh[(size_t)le * 65536 + k * 256 + n];
    u32 h, lo; split2(v, h, lo);
    dH[i] = (ushort_t)h; dL[i] = (ushort_t)lo;
}

__global__ __launch_bounds__(256) void prep_w0(const float* __restrict__ W0,
                                               ushort_t* __restrict__ dH, ushort_t* __restrict__ dL) {
    int i = blockIdx.x * 256 + threadIdx.x;
    if (i >= W0_TOT) return;
    int j = i & 7, l = (i >> 3) & 63, ctg = (i >> 9) & 7, e = i >> 12;
    int k = ((l >> 5) << 3) + j;       // 0..15, valid < 6
    int n = ctg * 32 + (l & 31);
    float v = (k < IN_DIM) ? W0[(e * IN_DIM + k) * 256 + n] : 0.0f;
    u32 h, lo; split2(v, h, lo);
    dH[i] = (ushort_t)h; dL[i] = (ushort_t)lo;
}

__global__ __launch_bounds__(256) void prep_wf(const float* __restrict__ Wf,
                                               ushort_t* __restrict__ dH, ushort_t* __restrict__ dL) {
    int i = blockIdx.x * 256 + threadIdx.x;
    if (i >= WF_TOT) return;
    int e = i / WF_PER;
    int idx = i - e * WF_PER;
    int j = idx & 7, l = (idx >> 3) & 63, g = idx >> 9;  // g = s*7+ct, 0..111
    int s = g / 7, ct = g - s * 7;
    int k = s * 16 + ((l >> 5) << 3) + j;
    int n = ct * 32 + (l & 31);
    float v = (n < OUT_DIM) ? Wf[((size_t)e * 256 + k) * OUT_DIM + n] : 0.0f;
    u32 h, lo; split2(v, h, lo);
    dH[i] = (ushort_t)h; dL[i] = (ushort_t)lo;
}

__global__ __launch_bounds__(256) void prep_x(const float* __restrict__ x,
                                              ushort_t* __restrict__ dH, ushort_t* __restrict__ dL) {
    int i = blockIdx.x * 256 + threadIdx.x;
    if (i >= X_TOT) return;
    int j = i & 7, l = (i >> 3) & 63, rt = i >> 9;   // rt = 0..511
    int row = rt * 32 + (l & 31);
    int k = ((l >> 5) << 3) + j;
    float v = (k < IN_DIM) ? x[row * IN_DIM + k] : 0.0f;
    u32 h, lo; split2(v, h, lo);
    dH[i] = (ushort_t)h; dL[i] = (ushort_t)lo;
}

// out[b][jo] = 0.1 * (P[e1][b][jo-base(e1)] + (e2!=e1 ? P[e2][b][jo-base(e2)] : 0))
__global__ __launch_bounds__(256) void reduce_mean(const float* __restrict__ P,
                                                   float* __restrict__ out) {
    int i = blockIdx.x * 256 + threadIdx.x;
    if (i >= BATCH * OUT_DIM) return;
    int b = i / OUT_DIM, jo = i - b * OUT_DIM;
    int f0 = jo * 10;
    int e1 = f0 / OUT_DIM;
    int e2 = (f0 + 9) / OUT_DIM;
    int g1 = jo - (e1 * OUT_DIM) / 10;
    float s = P[((size_t)e1 * BATCH + b) * NG + g1];
    if (e2 != e1) {
        int g2 = jo - (e2 * OUT_DIM) / 10;
        s += P[((size_t)e2 * BATCH + b) * NG + g2];
    }
    out[i] = 0.1f * s;
}

#define MFMA32(A, B, C) __builtin_amdgcn_mfma_f32_32x32x16_bf16((A), (B), (C), 0, 0, 0)

// ---------------- fused MLP: 32x32x16 split-bf16, 64x64 wave tiles ----------------
// grid 2560 (XCD-swizzled); 256 threads = 4 waves; wave cg owns cols
// [cg*64, cg*64+64) of this WG's 64 batch rows (mt=2 row-tiles x ct=2 col-tiles,
// 12 MFMAs per k-step). LDS 67.6 KB -> 2 WG/CU (8 waves/CU). No global atomics.
__global__ __launch_bounds__(256, 2)
void mlp_mfma(const ushort_t* __restrict__ wsU,
              const float* __restrict__ b0g, const float* __restrict__ bhg,
              const float* __restrict__ bfg, float* __restrict__ Pws) {
    __shared__ __align__(16) u32 smem[16896];            // 67,584 B, aliased:
    ushort_t* actH = (ushort_t*)smem;                    //   [64][RS] hi plane
    ushort_t* actL = actH + RT * RS;                     //   [64][RS] lo plane
    float*    yst  = (float*)smem;                       //   [64][YS] final-y staging

    const int tid  = threadIdx.x;
    const int lane = tid & 63;
    const int cg   = tid >> 6;        // wave 0..3
    const int l31  = lane & 31;
    const int lh   = lane >> 5;       // 0..1
    const int ctg0 = cg * 2;

    // XCD-aware bijective swizzle: 2560 WGs, 8 XCDs, 320/XCD
    const int bid  = blockIdx.x;
    const int work = (bid & 7) * 320 + (bid >> 3);
    const int e    = work >> 8;       // ensemble 0..9
    const int rb   = work & 255;      // 64-row block 0..255
    const int rowWG = rb * RT;

    const size_t lo8 = (size_t)lane * 8;
    const ushort_t* arH0 = actH + l31 * RS;
    const ushort_t* arL0 = actL + l31 * RS;
    const ushort_t* arH1 = actH + (32 + l31) * RS;
    const ushort_t* arL1 = actL + (32 + l31) * RS;
    const int rowb = lh * 4;          // epilogue row base within 32-tile

    f32x16 acc[2][2];
    bf16x8 Bc0, Bc1, Bc2, Bc3;        // current B: [ct0 hi, ct0 lo, ct1 hi, ct1 lo]
    bf16x8 aH[2], aL[2];

    // ================ layer 0 (K padded 6->16, single k-step) ================
    {
        const ushort_t* B0H = wsU + O_W0H + (size_t)e * W0_PER;
        const ushort_t* B0L = wsU + O_W0L + (size_t)e * W0_PER;
        Bc0 = *(const bf16x8*)(B0H + (size_t)ctg0 * 512 + lo8);
        Bc1 = *(const bf16x8*)(B0L + (size_t)ctg0 * 512 + lo8);
        Bc2 = *(const bf16x8*)(B0H + (size_t)(ctg0 + 1) * 512 + lo8);
        Bc3 = *(const bf16x8*)(B0L + (size_t)(ctg0 + 1) * 512 + lo8);
#pragma unroll
        for (int mt = 0; mt < 2; ++mt) {
            size_t xoff = ((size_t)(rb * 2 + mt) * 64 + lane) * 8;
            aH[mt] = *(const bf16x8*)(wsU + O_XH + xoff);
            aL[mt] = *(const bf16x8*)(wsU + O_XL + xoff);
        }
        // prefetch hidden layer 0, s=0 B
        const ushort_t* BH0 = wsU + O_WHH + (size_t)e * WH_PER;
        const ushort_t* BL0 = wsU + O_WHL + (size_t)e * WH_PER;
        bf16x8 Bn0 = *(const bf16x8*)(BH0 + (size_t)ctg0 * 512 + lo8);
        bf16x8 Bn1 = *(const bf16x8*)(BL0 + (size_t)ctg0 * 512 + lo8);
        bf16x8 Bn2 = *(const bf16x8*)(BH0 + (size_t)(ctg0 + 1) * 512 + lo8);
        bf16x8 Bn3 = *(const bf16x8*)(BL0 + (size_t)(ctg0 + 1) * 512 + lo8);
        __builtin_amdgcn_sched_barrier(0);

        f32x16 z = 0.0f;
#pragma unroll
        for (int mt = 0; mt < 2; ++mt) {
            f32x16 a0 = z, a1 = z;
            a0 = MFMA32(aH[mt], Bc0, a0);
            a0 = MFMA32(aL[mt], Bc0, a0);
            a0 = MFMA32(aH[mt], Bc1, a0);
            a1 = MFMA32(aH[mt], Bc2, a1);
            a1 = MFMA32(aL[mt], Bc2, a1);
            a1 = MFMA32(aH[mt], Bc3, a1);
            acc[mt][0] = a0; acc[mt][1] = a1;
        }

        float bv0 = b0g[e * NU + ctg0 * 32 + l31];
        float bv1 = b0g[e * NU + (ctg0 + 1) * 32 + l31];
        int colA = ctg0 * 32 + l31, colB = colA + 32;
#pragma unroll
        for (int mt = 0; mt < 2; ++mt)
#pragma unroll
            for (int r = 0; r < 16; ++r) {
                int row = mt * 32 + rowb + (r & 3) + 8 * (r >> 2);
                float f0 = fmaxf(acc[mt][0][r] + bv0, 0.0f);
                float f1 = fmaxf(acc[mt][1][r] + bv1, 0.0f);
                u32 h0, q0, h1, q1;
                split2(f0, h0, q0); split2(f1, h1, q1);
                actH[row * RS + colA] = (ushort_t)h0; actL[row * RS + colA] = (ushort_t)q0;
                actH[row * RS + colB] = (ushort_t)h1; actL[row * RS + colB] = (ushort_t)q1;
            }
        Bc0 = Bn0; Bc1 = Bn1; Bc2 = Bn2; Bc3 = Bn3;
        __syncthreads();
    }

    // ================ 7 hidden layers (K=256, 16 k-steps, A+B pipelined) ================
    const ushort_t* BH = wsU + O_WHH + (size_t)e * WH_PER;
    const ushort_t* BL = wsU + O_WHL + (size_t)e * WH_PER;
#pragma unroll 1
    for (int L = 0; L < NHID; ++L) {
        float bv0 = bhg[(size_t)(L * ENS + e) * NU + ctg0 * 32 + l31];
        float bv1 = bhg[(size_t)(L * ENS + e) * NU + (ctg0 + 1) * 32 + l31];
        f32x16 z = 0.0f;
#pragma unroll
        for (int mt = 0; mt < 2; ++mt) { acc[mt][0] = z; acc[mt][1] = z; }
        // A for s=0
        aH[0] = *(const bf16x8*)(arH0 + lh * 8);
        aL[0] = *(const bf16x8*)(arL0 + lh * 8);
        aH[1] = *(const bf16x8*)(arH1 + lh * 8);
        aL[1] = *(const bf16x8*)(arL1 + lh * 8);

#pragma unroll
        for (int s = 0; s < 16; ++s) {
            bf16x8 aHn[2], aLn[2], Bn0, Bn1, Bn2, Bn3;
            if (s < 15) {
                int kn = (s + 1) * 16 + lh * 8;
                aHn[0] = *(const bf16x8*)(arH0 + kn);
                aLn[0] = *(const bf16x8*)(arL0 + kn);
                aHn[1] = *(const bf16x8*)(arH1 + kn);
                aLn[1] = *(const bf16x8*)(arL1 + kn);
                const ushort_t* ph = BH + (size_t)((s + 1) * 8 + ctg0) * 512;
                const ushort_t* pl = BL + (size_t)((s + 1) * 8 + ctg0) * 512;
                Bn0 = *(const bf16x8*)(ph + lo8);
                Bn1 = *(const bf16x8*)(pl + lo8);
                Bn2 = *(const bf16x8*)(ph + 512 + lo8);
                Bn3 = *(const bf16x8*)(pl + 512 + lo8);
            }
            __builtin_amdgcn_sched_barrier(0);
#pragma unroll
            for (int mt = 0; mt < 2; ++mt) {
                f32x16 a0 = acc[mt][0], a1 = acc[mt][1];
                a0 = MFMA32(aH[mt], Bc0, a0);
                a1 = MFMA32(aH[mt], Bc2, a1);
                a0 = MFMA32(aL[mt], Bc0, a0);
                a1 = MFMA32(aL[mt], Bc2, a1);
                a0 = MFMA32(aH[mt], Bc1, a0);
                a1 = MFMA32(aH[mt], Bc3, a1);
                acc[mt][0] = a0; acc[mt][1] = a1;
            }
            if (s < 15) {
                aH[0] = aHn[0]; aL[0] = aLn[0];
                aH[1] = aHn[1]; aL[1] = aLn[1];
                Bc0 = Bn0; Bc1 = Bn1; Bc2 = Bn2; Bc3 = Bn3;
            }
        }

        // prefetch next layer's s=0 B (or final layer's) before the barriers
        if (L < NHID - 1) {
            const ushort_t* nh = BH + (size_t)ENS * WH_PER;
            const ushort_t* nl = BL + (size_t)ENS * WH_PER;
            Bc0 = *(const bf16x8*)(nh + (size_t)ctg0 * 512 + lo8);
            Bc1 = *(const bf16x8*)(nl + (size_t)ctg0 * 512 + lo8);
            Bc2 = *(const bf16x8*)(nh + (size_t)(ctg0 + 1) * 512 + lo8);
            Bc3 = *(const bf16x8*)(nl + (size_t)(ctg0 + 1) * 512 + lo8);
        } else {
            const ushort_t* fh = wsU + O_WFH + (size_t)e * WF_PER;
            const ushort_t* fl = wsU + O_WFL + (size_t)e * WF_PER;
            int c0 = ctg0, c1 = (ctg0 + 1 > 6) ? 6 : ctg0 + 1;
            if (c0 > 6) c0 = 6;
            Bc0 = *(const bf16x8*)(fh + (size_t)c0 * 512 + lo8);
            Bc1 = *(const bf16x8*)(fl + (size_t)c0 * 512 + lo8);
            Bc2 = *(const bf16x8*)(fh + (size_t)c1 * 512 + lo8);
            Bc3 = *(const bf16x8*)(fl + (size_t)c1 * 512 + lo8);
        }

        __syncthreads();   // all act reads of this layer done before overwrite
        int colA = ctg0 * 32 + l31, colB = colA + 32;
#pragma unroll
        for (int mt = 0; mt < 2; ++mt)
#pragma unroll
            for (int r = 0; r < 16; ++r) {
                int row = mt * 32 + rowb + (r & 3) + 8 * (r >> 2);
                float f0 = fmaxf(acc[mt][0][r] + bv0, 0.0f);
                float f1 = fmaxf(acc[mt][1][r] + bv1, 0.0f);
                u32 h0, q0, h1, q1;
                split2(f0, h0, q0); split2(f1, h1, q1);
                actH[row * RS + colA] = (ushort_t)h0; actL[row * RS + colA] = (ushort_t)q0;
                actH[row * RS + colB] = (ushort_t)h1; actL[row * RS + colB] = (ushort_t)q1;
            }
        __syncthreads();
        BH += (size_t)ENS * WH_PER;
        BL += (size_t)ENS * WH_PER;
    }

    // ================ final layer (N padded 201->224 = 7 ct-tiles) ================
    {
        const ushort_t* FH = wsU + O_WFH + (size_t)e * WF_PER;
        const ushort_t* FL = wsU + O_WFL + (size_t)e * WF_PER;
        int c0 = (ctg0 > 6) ? 6 : ctg0;
        int c1 = (ctg0 + 1 > 6) ? 6 : ctg0 + 1;
        f32x16 z = 0.0f;
#pragma unroll
        for (int mt = 0; mt < 2; ++mt) { acc[mt][0] = z; acc[mt][1] = z; }
        aH[0] = *(const bf16x8*)(arH0 + lh * 8);
        aL[0] = *(const bf16x8*)(arL0 + lh * 8);
        aH[1] = *(const bf16x8*)(arH1 + lh * 8);
        aL[1] = *(const bf16x8*)(arL1 + lh * 8);

#pragma unroll
        for (int s = 0; s < 16; ++s) {
            bf16x8 aHn[2], aLn[2], Bn0, Bn1, Bn2, Bn3;
            if (s < 15) {
                int kn = (s + 1) * 16 + lh * 8;
                aHn[0] = *(const bf16x8*)(arH0 + kn);
                aLn[0] = *(const bf16x8*)(arL0 + kn);
                aHn[1] = *(const bf16x8*)(arH1 + kn);
                aLn[1] = *(const bf16x8*)(arL1 + kn);
                Bn0 = *(const bf16x8*)(FH + (size_t)((s + 1) * 7 + c0) * 512 + lo8);
                Bn1 = *(const bf16x8*)(FL + (size_t)((s + 1) * 7 + c0) * 512 + lo8);
                Bn2 = *(const bf16x8*)(FH + (size_t)((s + 1) * 7 + c1) * 512 + lo8);
                Bn3 = *(const bf16x8*)(FL + (size_t)((s + 1) * 7 + c1) * 512 + lo8);
            }
            __builtin_amdgcn_sched_barrier(0);
#pragma unroll
            for (int mt = 0; mt < 2; ++mt) {
                f32x16 a0 = acc[mt][0], a1 = acc[mt][1];
                a0 = MFMA32(aH[mt], Bc0, a0);
                a1 = MFMA32(aH[mt], Bc2, a1);
                a0 = MFMA32(aL[mt], Bc0, a0);
                a1 = MFMA32(aL[mt], Bc2, a1);
                a0 = MFMA32(aH[mt], Bc1, a0);
                a1 = MFMA32(aH[mt], Bc3, a1);
                acc[mt][0] = a0; acc[mt][1] = a1;
            }
            if (s < 15) {
                aH[0] = aHn[0]; aL[0] = aLn[0];
                aH[1] = aHn[1]; aL[1] = aLn[1];
                Bc0 = Bn0; Bc1 = Bn1; Bc2 = Bn2; Bc3 = Bn3;
            }
        }

        // ---- NO atomics: stage y into LDS, reduce groups-of-10, store partials ----
        int o0 = ctg0 * 32 + l31;
        int o1 = (ctg0 + 1) * 32 + l31;
        bool v0 = (o0 < OUT_DIM);
        bool v1 = (ctg0 + 1 < 7) && (o1 < OUT_DIM);
        float bf0 = v0 ? bfg[e * OUT_DIM + o0] : 0.0f;
        float bf1 = v1 ? bfg[e * OUT_DIM + o1] : 0.0f;

        __syncthreads();   // all act reads done; safe to overwrite smem with yst
#pragma unroll
        for (int mt = 0; mt < 2; ++mt)
#pragma unroll
            for (int r = 0; r < 16; ++r) {
                int row = mt * 32 + rowb + (r & 3) + 8 * (r >> 2);
                if (v0) yst[row * YS + o0] = acc[mt][0][r] + bf0;
                if (v1) yst[row * YS + o1] = acc[mt][1][r] + bf1;
            }
        __syncthreads();

        // partial sums: P[e][rowWG+row][g] = sum over flatc in [jo*10, jo*10+10)
        // intersected with this ensemble's block [201e, 201e+201)
        const int base_jo = (e * OUT_DIM) / 10;
        const int e201 = e * OUT_DIM;
        for (int it = tid; it < RT * NG; it += 256) {
            int row = it / NG;
            int g   = it - row * NG;
            int jo  = base_jo + g;
            int f0  = jo * 10;
            float s = 0.0f;
#pragma unroll
            for (int d = 0; d < 10; ++d) {
                int oo = f0 + d - e201;
                if (oo >= 0 && oo < OUT_DIM) s += yst[row * YS + oo];
            }
            Pws[((size_t)e * BATCH + rowWG + row) * NG + g] = s;
        }
    }
}

extern "C" void kernel_launch(void* const* d_in, const int* in_sizes, int n_in,
                              void* d_out, int out_size, void* d_ws, size_t ws_size,
                              hipStream_t stream) {
    const float* x  = (const float*)d_in[0];
    const float* W0 = (const float*)d_in[1];
    const float* b0 = (const float*)d_in[2];
    const float* Wh = (const float*)d_in[3];
    const float* bh = (const float*)d_in[4];
    const float* Wf = (const float*)d_in[5];
    const float* bf = (const float*)d_in[6];
    float* out = (float*)d_out;
    ushort_t* ws = (ushort_t*)d_ws;            // needs ~36 MB
    float* Pws = (float*)(ws + O_P);           // P[ENS][BATCH][NG]

    prep_wh<<<(WH_TOT + 255) / 256, 256, 0, stream>>>(Wh, ws + O_WHH, ws + O_WHL);
    prep_w0<<<(W0_TOT + 255) / 256, 256, 0, stream>>>(W0, ws + O_W0H, ws + O_W0L);
    prep_wf<<<(WF_TOT + 255) / 256, 256, 0, stream>>>(Wf, ws + O_WFH, ws + O_WFL);
    prep_x <<<(X_TOT  + 255) / 256, 256, 0, stream>>>(x,  ws + O_XH,  ws + O_XL);

    mlp_mfma<<<dim3(BATCH / RT * ENS), 256, 0, stream>>>(ws, b0, bh, bf, Pws);
    reduce_mean<<<(BATCH * OUT_DIM + 255) / 256, 256, 0, stream>>>(Pws, out);
}